// Round 7
// baseline (546.865 us; speedup 1.0000x reference)
//
#include <hip/hip_runtime.h>

#define NCAT 32
#define NTOK 512
#define HID  512
#define EMB  1024
#define DSTATE 192
#define CHUNK 32
#define MAXW 48

// ws layout:
//   [0,128)        int cnt[32]
//   [128,136)      int nW[1]        (chunks of 32 tokens; sum ceil(n/32) <= 47)
//   [256,448)      int work[48]     entries: cat | (chunk<<8)
//   [1024,66560)   int toklist[32][512]

__global__ __launch_bounds__(512) void bucket_kernel(
    const int* __restrict__ ids, int* __restrict__ cnt, int* __restrict__ nW,
    int* __restrict__ work, int* __restrict__ toklist)
{
    __shared__ int scnt[NCAT];
    const int tid = threadIdx.x;
    if (tid < NCAT) scnt[tid] = 0;
    __syncthreads();
    const int c = ids[tid];                       // 512 threads == 512 tokens
    const int pos = atomicAdd(&scnt[c], 1);       // LDS atomic: cheap
    toklist[c * NTOK + pos] = tid;
    __syncthreads();
    if (tid == 0) {
        int n1 = 0;
        for (int cc = 0; cc < NCAT; ++cc) {
            const int n = scnt[cc];
            cnt[cc] = n;
            for (int ch = 0; ch * CHUNK < n; ++ch) work[n1++] = cc | (ch << 8);
        }
        nW[0] = n1;
    }
}

// Fused layer1+layer2. grid (48 slots, 4 mod, 2 colhalf), 256 threads,
// 2 blocks/CU (LDS 72 KB, VGPR capped by launch_bounds). W2 has NO
// cross-thread reuse -> stream it global->VGPR (no LDS FIFO, no barriers
// in the k-loop). Static double-buffered 8-row tiles, 16 loads in flight
// per wave; compiler emits counted vmcnt; sched_barrier(0) pins
// issue-before-compute. Only H (wave-broadcast) lives in LDS.
__global__ __launch_bounds__(256, 2) void fused_kernel(
    const float* __restrict__ state,
    const int* __restrict__ cnt, const int* __restrict__ toklist,
    const int* __restrict__ nW, const int* __restrict__ work,
    const float* __restrict__ W1_0, const float* __restrict__ W1_1,
    const float* __restrict__ W1_2, const float* __restrict__ W1_3,
    const float* __restrict__ b1_0, const float* __restrict__ b1_1,
    const float* __restrict__ b1_2, const float* __restrict__ b1_3,
    const float* __restrict__ W2_0, const float* __restrict__ W2_1,
    const float* __restrict__ W2_2, const float* __restrict__ W2_3,
    const float* __restrict__ b2_0, const float* __restrict__ b2_1,
    const float* __restrict__ b2_2, const float* __restrict__ b2_3,
    const float* __restrict__ te_0, const float* __restrict__ te_1,
    const float* __restrict__ te_2, const float* __restrict__ te_3,
    float* __restrict__ out)
{
    const int slot = blockIdx.x, mod = blockIdx.y, z = blockIdx.z;
    if (slot >= nW[0]) return;
    const int ent = work[slot];
    const int cat = ent & 255, chunk = ent >> 8;
    const int nC = cnt[cat];
    const int start = chunk * CHUNK;
    int nThis = nC - start;
    if (nThis > CHUNK) nThis = CHUNK;
    const int tid = threadIdx.x;
    const int tg = tid >> 6;                       // wave id: 8-token group
    const int cg = tid & 63;                       // col group

    const int L   = (mod < 2) ? 64 : 32;
    const int off = (mod == 0) ? 0 : (mod == 1) ? 64 : (mod == 2) ? 128 : 160;

    __shared__ float sX[64 * 32];                  // [k][t], 8 KiB
    __shared__ float sH[512 * 32];                 // [k][token-quad swz], 64 KiB
    __shared__ int sTok[CHUNK];

    if (tid < CHUNK) sTok[tid] = (tid < nThis) ? toklist[cat * NTOK + start + tid] : 0;
    __syncthreads();

    {   // stage sX transposed: tt owns token tt, kg = tid>>5 owns L/8 k-rows
        const int tt = tid & 31, kg = tid >> 5;
        const int rpk = L >> 3;                    // 8 or 4 rows per kg
        const float* src = state + (size_t)sTok[tt] * DSTATE + off + kg * rpk;
        const bool ok = tt < nThis;
        for (int j = 0; j < (rpk >> 2); ++j) {
            float4 v = make_float4(0.f, 0.f, 0.f, 0.f);
            if (ok) v = ((const float4*)src)[j];
            const int k0 = kg * rpk + (j << 2);
            sX[(k0 + 0) * 32 + tt] = v.x;
            sX[(k0 + 1) * 32 + tt] = v.y;
            sX[(k0 + 2) * 32 + tt] = v.z;
            sX[(k0 + 3) * 32 + tt] = v.w;
        }
    }
    __syncthreads();

    // ---- layer1: thread owns H cols {2tid, 2tid+1} across 32 tokens ----
    const float* W1 = (mod == 0) ? W1_0 : (mod == 1) ? W1_1 : (mod == 2) ? W1_2 : W1_3;
    const float* b1 = (mod == 0) ? b1_0 : (mod == 1) ? b1_1 : (mod == 2) ? b1_2 : b1_3;
    const float* W1c = W1 + (size_t)cat * L * HID + 2 * tid;

    float2 hacc[32];
#pragma unroll
    for (int t = 0; t < 32; ++t) hacc[t] = make_float2(0.f, 0.f);

#pragma unroll 4
    for (int k = 0; k < L; ++k) {
        const float2 w = *(const float2*)(W1c + (size_t)k * HID);
        const float4* xp = (const float4*)(sX + k * 32);
#pragma unroll
        for (int q = 0; q < 8; ++q) {
            const float4 x4 = xp[q];
            hacc[4*q+0].x += x4.x * w.x; hacc[4*q+0].y += x4.x * w.y;
            hacc[4*q+1].x += x4.y * w.x; hacc[4*q+1].y += x4.y * w.y;
            hacc[4*q+2].x += x4.z * w.x; hacc[4*q+2].y += x4.z * w.y;
            hacc[4*q+3].x += x4.w * w.x; hacc[4*q+3].y += x4.w * w.y;
        }
    }
    {   // bias + relu; write sH rows {2tid,2tid+1}; token-quad q at q^(tid&7)
        // (write: lanes spread over quad-slots; read side is wave-uniform
        //  broadcast at slot tq ^ ((k>>1)&7) -- verified exact in R6)
        const float2 bb = *(const float2*)(b1 + cat * HID + 2 * tid);
        float4* s4 = (float4*)sH;
        const int key = tid & 7;
        const int r0 = 2 * tid, r1 = 2 * tid + 1;
#pragma unroll
        for (int q = 0; q < 8; ++q) {
            float4 v0, v1;
            v0.x = fmaxf(hacc[4*q+0].x + bb.x, 0.f);
            v0.y = fmaxf(hacc[4*q+1].x + bb.x, 0.f);
            v0.z = fmaxf(hacc[4*q+2].x + bb.x, 0.f);
            v0.w = fmaxf(hacc[4*q+3].x + bb.x, 0.f);
            v1.x = fmaxf(hacc[4*q+0].y + bb.y, 0.f);
            v1.y = fmaxf(hacc[4*q+1].y + bb.y, 0.f);
            v1.z = fmaxf(hacc[4*q+2].y + bb.y, 0.f);
            v1.w = fmaxf(hacc[4*q+3].y + bb.y, 0.f);
            s4[r0 * 8 + (q ^ key)] = v0;
            s4[r1 * 8 + (q ^ key)] = v1;
        }
    }
    __syncthreads();                               // sH ready for all waves

    // ---- layer2: register-streamed W2, barrier-free ----
    const float* W2 = (mod == 0) ? W2_0 : (mod == 1) ? W2_1 : (mod == 2) ? W2_2 : W2_3;
    const int wcol = cg << 2;                      // quad A col; quad B at +256
    const float* Wc = W2 + (size_t)cat * (HID * EMB) + z * 512 + wcol;

    const int hbase = tg << 3;                     // token base
    const int tq0   = tg << 1;                     // token-quad base
    const bool act  = hbase < nThis;

    float4 a0[8], a1[8];
#pragma unroll
    for (int i = 0; i < 8; ++i) {
        a0[i] = make_float4(0.f, 0.f, 0.f, 0.f);
        a1[i] = make_float4(0.f, 0.f, 0.f, 0.f);
    }

#define LOAD_TILE(T, ba, bb) do {                                               \
        const float* pt_ = Wc + (size_t)(T) * 8 * EMB;                          \
        _Pragma("unroll")                                                       \
        for (int r_ = 0; r_ < 8; ++r_) {                                        \
            ba[r_] = *(const float4*)(pt_ + (size_t)r_ * EMB);                  \
            bb[r_] = *(const float4*)(pt_ + (size_t)r_ * EMB + 256);            \
        }                                                                       \
    } while (0)

#define FMA2(i, s) a0[i].x += (s)*w0.x; a0[i].y += (s)*w0.y;                    \
                   a0[i].z += (s)*w0.z; a0[i].w += (s)*w0.w;                    \
                   a1[i].x += (s)*w1.x; a1[i].y += (s)*w1.y;                    \
                   a1[i].z += (s)*w1.z; a1[i].w += (s)*w1.w;

#define FMA_TILE(T, ba, bb) do {                                                \
        _Pragma("unroll")                                                       \
        for (int r_ = 0; r_ < 8; ++r_) {                                        \
            const int k_  = (T) * 8 + r_;                                       \
            const int kk_ = (k_ >> 1) & 7;                                      \
            const float4 h0 = ((const float4*)sH)[k_ * 8 + (tq0 ^ kk_)];        \
            const float4 h1 = ((const float4*)sH)[k_ * 8 + ((tq0 + 1) ^ kk_)];  \
            const float4 w0 = ba[r_];                                           \
            const float4 w1 = bb[r_];                                           \
            FMA2(0, h0.x) FMA2(1, h0.y) FMA2(2, h0.z) FMA2(3, h0.w)             \
            FMA2(4, h1.x) FMA2(5, h1.y) FMA2(6, h1.z) FMA2(7, h1.w)             \
        }                                                                       \
    } while (0)

    if (act) {
        float4 Aa[8], Ab[8], Ba[8], Bb[8];
        LOAD_TILE(0, Aa, Ab);
        __builtin_amdgcn_sched_barrier(0);
#pragma unroll 1
        for (int T = 0; T < 62; T += 2) {
            LOAD_TILE(T + 1, Ba, Bb);              // 16 loads in flight
            __builtin_amdgcn_sched_barrier(0);
            FMA_TILE(T, Aa, Ab);                   // waits vmcnt(16) on Aa/Ab
            LOAD_TILE(T + 2, Aa, Ab);
            __builtin_amdgcn_sched_barrier(0);
            FMA_TILE(T + 1, Ba, Bb);
        }
        LOAD_TILE(63, Ba, Bb);
        __builtin_amdgcn_sched_barrier(0);
        FMA_TILE(62, Aa, Ab);
        FMA_TILE(63, Ba, Bb);
    }
#undef LOAD_TILE
#undef FMA_TILE
#undef FMA2

    const float* b2 = (mod == 0) ? b2_0 : (mod == 1) ? b2_1 : (mod == 2) ? b2_2 : b2_3;
    const float* te = (mod == 0) ? te_0 : (mod == 1) ? te_1 : (mod == 2) ? te_2 : te_3;
    const int colA = z * 512 + wcol;
    const int colB = colA + 256;
    const float4 bA = *(const float4*)(b2 + cat * EMB + colA);
    const float4 bB = *(const float4*)(b2 + cat * EMB + colB);
    const float4 tA = *(const float4*)(te + colA);
    const float4 tB = *(const float4*)(te + colB);
#pragma unroll
    for (int i = 0; i < 8; ++i) {
        const int t = hbase + i;
        if (t >= nThis) break;
        float* op = out + (size_t)(sTok[t] * 4 + mod) * EMB;
        *(float4*)(op + colA) = make_float4(a0[i].x + bA.x + tA.x,
                                            a0[i].y + bA.y + tA.y,
                                            a0[i].z + bA.z + tA.z,
                                            a0[i].w + bA.w + tA.w);
        *(float4*)(op + colB) = make_float4(a1[i].x + bB.x + tB.x,
                                            a1[i].y + bB.y + tB.y,
                                            a1[i].z + bB.z + tB.z,
                                            a1[i].w + bB.w + tB.w);
    }
}

extern "C" void kernel_launch(void* const* d_in, const int* in_sizes, int n_in,
                              void* d_out, int out_size, void* d_ws, size_t ws_size,
                              hipStream_t stream) {
    const float* state = (const float*)d_in[0];
    const int*   ids   = (const int*)d_in[1];
    const float *W1[4], *b1[4], *W2[4], *b2[4], *te[4];
    for (int m = 0; m < 4; ++m) {
        W1[m] = (const float*)d_in[2 + 5 * m + 0];
        b1[m] = (const float*)d_in[2 + 5 * m + 1];
        W2[m] = (const float*)d_in[2 + 5 * m + 2];
        b2[m] = (const float*)d_in[2 + 5 * m + 3];
        te[m] = (const float*)d_in[2 + 5 * m + 4];
    }
    char* ws = (char*)d_ws;
    int*   cnt     = (int*)ws;
    int*   nW      = (int*)(ws + 128);
    int*   work    = (int*)(ws + 256);
    int*   toklist = (int*)(ws + 1024);
    float* out     = (float*)d_out;

    bucket_kernel<<<1, 512, 0, stream>>>(ids, cnt, nW, work, toklist);
    fused_kernel<<<dim3(MAXW, 4, 2), 256, 0, stream>>>(
        state, cnt, toklist, nW, work,
        W1[0], W1[1], W1[2], W1[3],
        b1[0], b1[1], b1[2], b1[3],
        W2[0], W2[1], W2[2], W2[3],
        b2[0], b2[1], b2[2], b2[3],
        te[0], te[1], te[2], te[3], out);
}

// Round 8
// 343.894 us; speedup vs baseline: 1.5902x; 1.5902x over previous
//
#include <hip/hip_runtime.h>

#define NCAT 32
#define NTOK 512
#define HID  512
#define EMB  1024
#define DSTATE 192
#define CHUNK 32
#define MAXW 48

// ws layout:
//   [0,128)        int cnt[32]
//   [128,136)      int nW[1]        (chunks of 32 tokens; sum ceil(n/32) <= 47)
//   [256,448)      int work[48]     entries: cat | (chunk<<8)
//   [1024,66560)   int toklist[32][512]

__global__ __launch_bounds__(512) void bucket_kernel(
    const int* __restrict__ ids, int* __restrict__ cnt, int* __restrict__ nW,
    int* __restrict__ work, int* __restrict__ toklist)
{
    __shared__ int scnt[NCAT];
    const int tid = threadIdx.x;
    if (tid < NCAT) scnt[tid] = 0;
    __syncthreads();
    const int c = ids[tid];                       // 512 threads == 512 tokens
    const int pos = atomicAdd(&scnt[c], 1);       // LDS atomic: cheap
    toklist[c * NTOK + pos] = tid;
    __syncthreads();
    if (tid == 0) {
        int n1 = 0;
        for (int cc = 0; cc < NCAT; ++cc) {
            const int n = scnt[cc];
            cnt[cc] = n;
            for (int ch = 0; ch * CHUNK < n; ++ch) work[n1++] = cc | (ch << 8);
        }
        nW[0] = n1;
    }
}

// async global->LDS, 16 B per lane. LDS dest wave-uniform base (+lane*16 by HW).
__device__ __forceinline__ void async_copy16(void* lds_dst, const void* g_src) {
    __builtin_amdgcn_global_load_lds(
        (__attribute__((address_space(1))) void*)(g_src),
        (__attribute__((address_space(3))) void*)(lds_dst),
        16, 0, 0);
}

// Fused layer1+layer2, R6 pipeline at HALF the LDS (81920 B) -> 2 blocks/CU.
// K processed in two 256-row phases: sH holds one half; threads 128..255 hold
// their layer1 outputs in registers through phase A and write sH at the switch
// (raw lgkmcnt(0)+s_barrier -- __syncthreads would drain in-flight gll tiles).
// W2 streamed via global_load_lds, 3 bufs staged 2 ahead, counted vmcnt(4).
__global__ __launch_bounds__(256, 2) void fused_kernel(
    const float* __restrict__ state,
    const int* __restrict__ cnt, const int* __restrict__ toklist,
    const int* __restrict__ nW, const int* __restrict__ work,
    const float* __restrict__ W1_0, const float* __restrict__ W1_1,
    const float* __restrict__ W1_2, const float* __restrict__ W1_3,
    const float* __restrict__ b1_0, const float* __restrict__ b1_1,
    const float* __restrict__ b1_2, const float* __restrict__ b1_3,
    const float* __restrict__ W2_0, const float* __restrict__ W2_1,
    const float* __restrict__ W2_2, const float* __restrict__ W2_3,
    const float* __restrict__ b2_0, const float* __restrict__ b2_1,
    const float* __restrict__ b2_2, const float* __restrict__ b2_3,
    const float* __restrict__ te_0, const float* __restrict__ te_1,
    const float* __restrict__ te_2, const float* __restrict__ te_3,
    float* __restrict__ out)
{
    const int slot = blockIdx.x, mod = blockIdx.y, z = blockIdx.z;
    if (slot >= nW[0]) return;
    const int ent = work[slot];
    const int cat = ent & 255, chunk = ent >> 8;
    const int nC = cnt[cat];
    const int start = chunk * CHUNK;
    int nThis = nC - start;
    if (nThis > CHUNK) nThis = CHUNK;
    const int tid = threadIdx.x;
    const int tg = tid >> 6;                       // wave id: 8-token group
    const int cg = tid & 63;                       // col group

    const int L   = (mod < 2) ? 64 : 32;
    const int off = (mod == 0) ? 0 : (mod == 1) ? 64 : (mod == 2) ? 128 : 160;

    // flat 81920 B: sH = 256 rows x 32 floats (32 KB); 3 W tiles x 16 KB.
    // sX (8 KB) aliases W-tile 0 (used only before streaming starts).
    __shared__ __align__(16) float smem[20480];
    float* const sH  = smem;                       // [0, 8192)
    float* const wbB = smem + 8192;                // 3 x 4096 floats
    float* const sX  = smem + 8192;                // alias of wbB[0]

    {   // stage sX transposed [k][t]: tt owns token, kg = tid>>5 owns L/8 rows
        const int tt = tid & 31, kg = tid >> 5;
        const int rpk = L >> 3;                    // 8 or 4 rows per kg
        int tok = 0;
        if (tt < nThis) tok = toklist[cat * NTOK + start + tt];
        const float* src = state + (size_t)tok * DSTATE + off + kg * rpk;
        const bool ok = tt < nThis;
        for (int j = 0; j < (rpk >> 2); ++j) {
            float4 v = make_float4(0.f, 0.f, 0.f, 0.f);
            if (ok) v = ((const float4*)src)[j];
            const int k0 = kg * rpk + (j << 2);
            sX[(k0 + 0) * 32 + tt] = v.x;
            sX[(k0 + 1) * 32 + tt] = v.y;
            sX[(k0 + 2) * 32 + tt] = v.z;
            sX[(k0 + 3) * 32 + tt] = v.w;
        }
    }
    __syncthreads();

    // ---- layer1: thread owns H cols {2tid, 2tid+1} across 32 tokens ----
    const float* W1 = (mod == 0) ? W1_0 : (mod == 1) ? W1_1 : (mod == 2) ? W1_2 : W1_3;
    const float* b1 = (mod == 0) ? b1_0 : (mod == 1) ? b1_1 : (mod == 2) ? b1_2 : b1_3;
    const float* W1c = W1 + (size_t)cat * L * HID + 2 * tid;

    float2 hacc[32];
#pragma unroll
    for (int t = 0; t < 32; ++t) hacc[t] = make_float2(0.f, 0.f);

#pragma unroll 4
    for (int k = 0; k < L; ++k) {
        const float2 w = *(const float2*)(W1c + (size_t)k * HID);
        const float4* xp = (const float4*)(sX + k * 32);
#pragma unroll
        for (int q = 0; q < 8; ++q) {
            const float4 x4 = xp[q];
            hacc[4*q+0].x += x4.x * w.x; hacc[4*q+0].y += x4.x * w.y;
            hacc[4*q+1].x += x4.y * w.x; hacc[4*q+1].y += x4.y * w.y;
            hacc[4*q+2].x += x4.z * w.x; hacc[4*q+2].y += x4.z * w.y;
            hacc[4*q+3].x += x4.w * w.x; hacc[4*q+3].y += x4.w * w.y;
        }
    }
    {   // bias + relu in-register (hacc becomes final H values)
        const float2 bb = *(const float2*)(b1 + cat * HID + 2 * tid);
#pragma unroll
        for (int t = 0; t < 32; ++t) {
            hacc[t].x = fmaxf(hacc[t].x + bb.x, 0.f);
            hacc[t].y = fmaxf(hacc[t].y + bb.y, 0.f);
        }
    }

    // sH write: rows {2tid, 2tid+1} (mod 256), token-quad q at slot q^(tid&7).
    // Write side spreads lanes over quad-slots; read side is wave-uniform
    // broadcast at slot tq ^ ((k>>1)&7) -- k>>1 == tid for both rows (R6-exact).
#define WRITE_SH() do {                                                         \
        float4* s4_ = (float4*)sH;                                              \
        const int key_ = tid & 7;                                               \
        const int r0_ = (2 * tid) & 255;                                        \
        _Pragma("unroll")                                                       \
        for (int q_ = 0; q_ < 8; ++q_) {                                        \
            float4 v0_, v1_;                                                    \
            v0_.x = hacc[4*q_+0].x; v0_.y = hacc[4*q_+1].x;                     \
            v0_.z = hacc[4*q_+2].x; v0_.w = hacc[4*q_+3].x;                     \
            v1_.x = hacc[4*q_+0].y; v1_.y = hacc[4*q_+1].y;                     \
            v1_.z = hacc[4*q_+2].y; v1_.w = hacc[4*q_+3].y;                     \
            s4_[(r0_ + 0) * 8 + (q_ ^ key_)] = v0_;                             \
            s4_[(r0_ + 1) * 8 + (q_ ^ key_)] = v1_;                             \
        }                                                                       \
    } while (0)

    if (tid < 128) WRITE_SH();                     // phase A: k in [0,256)
    __syncthreads();                               // sH-A ready; sX dead

    // ---- layer2: stream 64 tiles of 8 rows x 512 cols ----
    const float* W2 = (mod == 0) ? W2_0 : (mod == 1) ? W2_1 : (mod == 2) ? W2_2 : W2_3;
    const float* Wc = W2 + (size_t)cat * (HID * EMB) + z * 512;
    const int wcol  = cg << 2;                     // quad A col; quad B at +256
    const int hbase = tg << 3;
    const int tq0   = tg << 1;
    const bool act  = hbase < nThis;

#define STAGE_TILE(T, wbase) do {                                               \
        const float* gsrc_ = Wc + (size_t)((T) * 8 + (tid >> 7)) * EMB          \
                             + ((tid & 127) << 2);                              \
        float* ldst_ = (wbase) + ((tid >> 6) << 8);                             \
        async_copy16(ldst_,        gsrc_);                                      \
        async_copy16(ldst_ + 1024, gsrc_ + 2 * EMB);                            \
        async_copy16(ldst_ + 2048, gsrc_ + 4 * EMB);                            \
        async_copy16(ldst_ + 3072, gsrc_ + 6 * EMB);                            \
    } while (0)

    float4 a0[8], a1[8];
#pragma unroll
    for (int i = 0; i < 8; ++i) {
        a0[i] = make_float4(0.f, 0.f, 0.f, 0.f);
        a1[i] = make_float4(0.f, 0.f, 0.f, 0.f);
    }

#define FMA2(i, s) a0[i].x += (s)*w0.x; a0[i].y += (s)*w0.y;                    \
                   a0[i].z += (s)*w0.z; a0[i].w += (s)*w0.w;                    \
                   a1[i].x += (s)*w1.x; a1[i].y += (s)*w1.y;                    \
                   a1[i].z += (s)*w1.z; a1[i].w += (s)*w1.w;

#define COMP_TILE(T, wbase) do {                                                \
        _Pragma("unroll")                                                       \
        for (int r_ = 0; r_ < 8; ++r_) {                                        \
            const int k_  = (T) * 8 + r_;                                       \
            const int kk_ = (k_ >> 1) & 7;                                      \
            const int kr_ = k_ & 255;                                           \
            const float4 h0 = ((const float4*)sH)[kr_ * 8 + (tq0 ^ kk_)];       \
            const float4 h1 = ((const float4*)sH)[kr_ * 8 + ((tq0 + 1) ^ kk_)]; \
            const float4 w0 = *(const float4*)((wbase) + r_ * 512 + wcol);      \
            const float4 w1 = *(const float4*)((wbase) + r_ * 512 + 256 + wcol);\
            FMA2(0, h0.x) FMA2(1, h0.y) FMA2(2, h0.z) FMA2(3, h0.w)             \
            FMA2(4, h1.x) FMA2(5, h1.y) FMA2(6, h1.z) FMA2(7, h1.w)             \
        }                                                                       \
    } while (0)

    STAGE_TILE(0, wbB);
    STAGE_TILE(1, wbB + 4096);
    asm volatile("s_waitcnt vmcnt(4)" ::: "memory");   // tile 0 landed
    __builtin_amdgcn_s_barrier();
    __builtin_amdgcn_sched_barrier(0);

    int bcur = 0;
#pragma unroll 1
    for (int T = 0; T < 32; ++T) {                 // phase A: k in [0,256)
        int bnx = bcur + 2; if (bnx >= 3) bnx -= 3;
        STAGE_TILE(T + 2, wbB + bnx * 4096);       // T+2 <= 33 always valid
        if (act) COMP_TILE(T, wbB + bcur * 4096);
        asm volatile("s_waitcnt vmcnt(4)" ::: "memory");
        __builtin_amdgcn_s_barrier();
        __builtin_amdgcn_sched_barrier(0);
        bcur += 1; if (bcur == 3) bcur = 0;
    }

    if (tid >= 128) WRITE_SH();                    // phase B: k in [256,512)
    asm volatile("s_waitcnt lgkmcnt(0)" ::: "memory");  // NOT __syncthreads:
    __builtin_amdgcn_s_barrier();                  // keep gll tiles in flight
    __builtin_amdgcn_sched_barrier(0);

#pragma unroll 1
    for (int T = 32; T < 64; ++T) {                // phase B
        int bnx = bcur + 2; if (bnx >= 3) bnx -= 3;
        if (T + 2 < 64) STAGE_TILE(T + 2, wbB + bnx * 4096);
        if (act) COMP_TILE(T, wbB + bcur * 4096);
        if (T < 63) {
            if (T + 2 < 64) { asm volatile("s_waitcnt vmcnt(4)" ::: "memory"); }
            else            { asm volatile("s_waitcnt vmcnt(0)" ::: "memory"); }
            __builtin_amdgcn_s_barrier();
            __builtin_amdgcn_sched_barrier(0);
        }
        bcur += 1; if (bcur == 3) bcur = 0;
    }
#undef STAGE_TILE
#undef COMP_TILE
#undef FMA2
#undef WRITE_SH

    const float* b2 = (mod == 0) ? b2_0 : (mod == 1) ? b2_1 : (mod == 2) ? b2_2 : b2_3;
    const float* te = (mod == 0) ? te_0 : (mod == 1) ? te_1 : (mod == 2) ? te_2 : te_3;
    const int colA = z * 512 + wcol;
    const int colB = colA + 256;
    const float4 bA = *(const float4*)(b2 + cat * EMB + colA);
    const float4 bB = *(const float4*)(b2 + cat * EMB + colB);
    const float4 tA = *(const float4*)(te + colA);
    const float4 tB = *(const float4*)(te + colB);
#pragma unroll
    for (int i = 0; i < 8; ++i) {
        const int t = hbase + i;
        if (t >= nThis) break;
        const int tok = toklist[cat * NTOK + start + t];
        float* op = out + (size_t)(tok * 4 + mod) * EMB;
        *(float4*)(op + colA) = make_float4(a0[i].x + bA.x + tA.x,
                                            a0[i].y + bA.y + tA.y,
                                            a0[i].z + bA.z + tA.z,
                                            a0[i].w + bA.w + tA.w);
        *(float4*)(op + colB) = make_float4(a1[i].x + bB.x + tB.x,
                                            a1[i].y + bB.y + tB.y,
                                            a1[i].z + bB.z + tB.z,
                                            a1[i].w + bB.w + tB.w);
    }
}

extern "C" void kernel_launch(void* const* d_in, const int* in_sizes, int n_in,
                              void* d_out, int out_size, void* d_ws, size_t ws_size,
                              hipStream_t stream) {
    const float* state = (const float*)d_in[0];
    const int*   ids   = (const int*)d_in[1];
    const float *W1[4], *b1[4], *W2[4], *b2[4], *te[4];
    for (int m = 0; m < 4; ++m) {
        W1[m] = (const float*)d_in[2 + 5 * m + 0];
        b1[m] = (const float*)d_in[2 + 5 * m + 1];
        W2[m] = (const float*)d_in[2 + 5 * m + 2];
        b2[m] = (const float*)d_in[2 + 5 * m + 3];
        te[m] = (const float*)d_in[2 + 5 * m + 4];
    }
    char* ws = (char*)d_ws;
    int*   cnt     = (int*)ws;
    int*   nW      = (int*)(ws + 128);
    int*   work    = (int*)(ws + 256);
    int*   toklist = (int*)(ws + 1024);
    float* out     = (float*)d_out;

    bucket_kernel<<<1, 512, 0, stream>>>(ids, cnt, nW, work, toklist);
    fused_kernel<<<dim3(MAXW, 4, 2), 256, 0, stream>>>(
        state, cnt, toklist, nW, work,
        W1[0], W1[1], W1[2], W1[3],
        b1[0], b1[1], b1[2], b1[3],
        W2[0], W2[1], W2[2], W2[3],
        b2[0], b2[1], b2[2], b2[3],
        te[0], te[1], te[2], te[3], out);
}